// Round 21
// baseline (161.771 us; speedup 1.0000x reference)
//
#include <hip/hip_runtime.h>

#define BATCH 8
#define SEQ   8192
#define NH    16
#define DP    64
#define ROWF  (NH*DP)        // 1024 floats = 4KB per t (all heads)
#define HGRP  4              // heads per block (1KB staging rows)
#define NTHR  512            // 8 waves = 4 heads x 2 n-halves
#define RSF   257            // f32 row stride in ring (2-way bank alias = free)

typedef __attribute__((ext_vector_type(8))) short bf16x8;
typedef __attribute__((ext_vector_type(4))) float f32x4;
typedef const __attribute__((address_space(1))) void* gptr_t;
typedef __attribute__((address_space(3))) void* lptr_t;

// round-to-nearest-even f32->bf16 pair pack: lo -> low 16 bits (even t = lower k)
static __device__ __forceinline__ unsigned pk2(float lo, float hi) {
    unsigned a = __builtin_bit_cast(unsigned, lo);
    unsigned b = __builtin_bit_cast(unsigned, hi);
    a = (a + 0x7FFFu + ((a >> 16) & 1u)) >> 16;
    b = (b + 0x7FFFu + ((b >> 16) & 1u)) & 0xFFFF0000u;
    return (a & 0xFFFFu) | b;
}

// ---------------------------------------------------------------------------
// k_partial (MFMA + deep global_load_lds ring): per (b,h,chunk):
// C[64p][64n] = sum_t (w*X)[t][p]*B[t][n]  (GEMM, K=t).
// r19/r20 lesson: register-staged pipelines get silently re-serialized by the
// RA (VGPR 80 < the 143 a 3-deep pipeline needs) -> phases wait a full loaded
// HBM round-trip. This round stages RAW f32 straight to an LDS ring of 8
// slots (8 t-rows each) via global_load_lds (zero VGPR), consumed one quad
// (32t = one mfma-K) per phase with COUNTED vmcnt(8) -- loads for quad q+2
// issued at end of phase q stay in flight across barriers (T3/T4). Weight
// mul + bf16 pack happen at fragment read. 64KB/CU in flight (vs r8's 16KB).
// ---------------------------------------------------------------------------
template<int NBLK>
__global__ __launch_bounds__(NTHR)
void k_partial(const float* __restrict__ Xg, const float* __restrict__ Ag,
               const float* __restrict__ Bg, float* __restrict__ part,
               float* __restrict__ blockA)
{
    constexpr int TB = SEQ / NBLK;    // 256 (NBLK=32)
    constexpr int Q  = TB / 64;       // 4
    constexpr int NQ = TB / 32;       // 8 quads (1 quad = 32 t = one mfma-K)

    __shared__ float XLf[8][8][RSF];  // ring: [slot][t_loc][head*64+p] raw f32
    __shared__ float BLf[8][8][RSF];  // 2 x 64.3 KB
    __shared__ float WT[HGRP][TB];    // weights (4-8 KB)

    const int gid  = blockIdx.x;            // b*(4*NBLK) + hg*NBLK + blk
    const int blk  = gid % NBLK;
    const int hg   = (gid / NBLK) & 3;
    const int b    = gid / (4 * NBLK);
    const int tid  = threadIdx.x;
    const int w    = tid >> 6;              // 0..7
    const int lane = tid & 63;
    const int hloc = w >> 1;                // head within group
    const int nh   = w & 1;                 // n-half
    const int h    = hg * HGRP + hloc;
    const int t0   = blk * TB;

    // ---- per-wave scan of A column h (redundant across the 2 waves/head) ----
    float c[Q];
    {
        const size_t abase = ((size_t)(b * SEQ + t0 + lane * Q)) * NH + h;
        float run = 0.f;
        #pragma unroll
        for (int k = 0; k < Q; ++k) { run += Ag[abase + (size_t)k * NH]; c[k] = run; }
    }
    float tsum = c[Q - 1], s = tsum;
    #pragma unroll
    for (int d = 1; d < 64; d <<= 1) {
        float o = __shfl_up(s, d, 64);
        if (lane >= d) s += o;
    }
    const float total = __shfl(s, 63, 64);
    const float excl  = s - tsum;
    if (nh == 0) {
        #pragma unroll
        for (int k = 0; k < Q; ++k)
            WT[hloc][lane * Q + k] = __expf(total - (excl + c[k]));
        if (lane == 63) blockA[(size_t)(b * NH + h) * NBLK + blk] = total;
    }

    f32x4 acc[4][2];
    #pragma unroll
    for (int mi = 0; mi < 4; ++mi)
        #pragma unroll
        for (int ni = 0; ni < 2; ++ni) acc[mi][ni] = (f32x4){0.f, 0.f, 0.f, 0.f};

    // ---- staging: wave w stages t_loc = w of each slot (1KB X + 1KB B) ----
    auto issueQuad = [&](int qq) {           // 4 slots, 8 global_load_lds per wave
        if (qq >= NQ) return;
        #pragma unroll
        for (int si = 0; si < 4; ++si) {
            const int sIdx = (4 * qq + si) & 7;
            const size_t rb = (size_t)(b * SEQ + t0 + 32 * qq + 8 * si + w) * ROWF
                              + hg * (HGRP * DP) + lane * 4;
            __builtin_amdgcn_global_load_lds((gptr_t)(Xg + rb),
                                             (lptr_t)&XLf[sIdx][w][0], 16, 0, 0);
            __builtin_amdgcn_global_load_lds((gptr_t)(Bg + rb),
                                             (lptr_t)&BLf[sIdx][w][0], 16, 0, 0);
        }
    };

    // ---- fragment assembly from raw f32 ring + weight mul + bf16 pack ----
    auto computeQuad = [&](int qq) {
        const int r  = lane & 15;
        const int kg = lane >> 4;            // lane's k-group reads slot 4qq+kg
        const int sIdx = (4 * qq + kg) & 7;
        float wts[8];
        #pragma unroll
        for (int j = 0; j < 8; ++j) wts[j] = WT[hloc][32 * qq + kg * 8 + j];
        uint4 av[4], bv[2];
        #pragma unroll
        for (int mi = 0; mi < 4; ++mi) {
            const int row = hloc * 64 + mi * 16 + r;
            float xs[8];
            #pragma unroll
            for (int j = 0; j < 8; ++j) xs[j] = XLf[sIdx][j][row] * wts[j];
            av[mi].x = pk2(xs[0], xs[1]); av[mi].y = pk2(xs[2], xs[3]);
            av[mi].z = pk2(xs[4], xs[5]); av[mi].w = pk2(xs[6], xs[7]);
        }
        #pragma unroll
        for (int ni = 0; ni < 2; ++ni) {
            const int row = hloc * 64 + nh * 32 + ni * 16 + r;
            float bs[8];
            #pragma unroll
            for (int j = 0; j < 8; ++j) bs[j] = BLf[sIdx][j][row];
            bv[ni].x = pk2(bs[0], bs[1]); bv[ni].y = pk2(bs[2], bs[3]);
            bv[ni].z = pk2(bs[4], bs[5]); bv[ni].w = pk2(bs[6], bs[7]);
        }
        #pragma unroll
        for (int mi = 0; mi < 4; ++mi) {
            const bf16x8 a = __builtin_bit_cast(bf16x8, av[mi]);
            #pragma unroll
            for (int ni = 0; ni < 2; ++ni)
                acc[mi][ni] = __builtin_amdgcn_mfma_f32_16x16x32_bf16(
                                  a, __builtin_bit_cast(bf16x8, bv[ni]),
                                  acc[mi][ni], 0, 0, 0);
        }
    };

    // ---- pipeline: quads 0,1 prefetched; per phase: counted-wait, compute,
    //      publish-read-done, issue quad+2 into the just-freed ring slots ----
    issueQuad(0);
    issueQuad(1);
    // WT visibility WITHOUT draining vmcnt (raw barrier, not __syncthreads)
    asm volatile("s_waitcnt lgkmcnt(0)" ::: "memory");
    __builtin_amdgcn_s_barrier();

    #pragma unroll 1
    for (int q = 0; q < NQ; ++q) {
        if (q < NQ - 1)
            asm volatile("s_waitcnt vmcnt(8)" ::: "memory");  // own quad-q loads done
        else
            asm volatile("s_waitcnt vmcnt(0)" ::: "memory");  // tail: only 8 left
        __builtin_amdgcn_s_barrier();           // quad q published by all waves
        __builtin_amdgcn_sched_barrier(0);
        computeQuad(q);
        asm volatile("s_waitcnt lgkmcnt(0)" ::: "memory");
        __builtin_amdgcn_s_barrier();           // all reads of quad q complete
        issueQuad(q + 2);                        // overwrite quad q's slots
    }

    // ---- epilogue: C/D layout (m89): col = lane&15, row = (lane>>4)*4 + reg ----
    float* dst = part + ((size_t)(b * NH + h) * NBLK + blk) * 4096;
    {
        const int r  = lane & 15;
        const int cg = lane >> 4;
        #pragma unroll
        for (int mi = 0; mi < 4; ++mi)
            #pragma unroll
            for (int ni = 0; ni < 2; ++ni)
                #pragma unroll
                for (int rr = 0; rr < 4; ++rr)
                    dst[(mi * 16 + cg * 4 + rr) * 64 + nh * 32 + ni * 16 + r] =
                        acc[mi][ni][rr];
    }
}

// ---------------------------------------------------------------------------
__global__ void k_scales(const float* __restrict__ blockA, float* __restrict__ scale,
                         int nblk)
{
    const int bh = blockIdx.x * blockDim.x + threadIdx.x;
    if (bh < BATCH * NH) {
        float run = 0.f;
        for (int c2 = nblk - 1; c2 >= 0; --c2) {
            scale[bh * nblk + c2] = __expf(run);
            run += blockA[bh * nblk + c2];
        }
    }
}

// ---------------------------------------------------------------------------
__global__ __launch_bounds__(256)
void k_combine(const float* __restrict__ part, const float* __restrict__ scale,
               float* __restrict__ out, int nblk)
{
    const int idx = blockIdx.x * 256 + threadIdx.x;
    const int bh  = idx >> 12;
    const int e   = idx & 4095;
    float r = 0.f;
    for (int q = 0; q < nblk; ++q)
        r += scale[bh * nblk + q] * part[((size_t)bh * nblk + q) * 4096 + e];
    out[idx] = r;
}

// ---------------------------------------------------------------------------
extern "C" void kernel_launch(void* const* d_in, const int* in_sizes, int n_in,
                              void* d_out, int out_size, void* d_ws, size_t ws_size,
                              hipStream_t stream)
{
    const float* X = (const float*)d_in[0];
    const float* A = (const float*)d_in[1];
    const float* B = (const float*)d_in[2];
    float* out     = (float*)d_out;

    const size_t need32 = ((size_t)BATCH * NH * 32 * 4096 + 2ull * BATCH * NH * 32) * 4;
    const int nblk = (ws_size >= need32) ? 32 : 16;

    float* part   = (float*)d_ws;
    float* blockA = part + (size_t)BATCH * NH * nblk * 4096;
    float* scale  = blockA + (size_t)BATCH * NH * nblk;

    if (nblk == 32)
        hipLaunchKernelGGL((k_partial<32>), dim3(BATCH * 4 * 32), dim3(NTHR), 0, stream,
                           X, A, B, part, blockA);
    else
        hipLaunchKernelGGL((k_partial<16>), dim3(BATCH * 4 * 16), dim3(NTHR), 0, stream,
                           X, A, B, part, blockA);

    hipLaunchKernelGGL(k_scales, dim3(1), dim3(128), 0, stream, blockA, scale, nblk);
    hipLaunchKernelGGL(k_combine, dim3((BATCH * NH * 4096) / 256), dim3(256), 0, stream,
                       part, scale, out, nblk);
}

// Round 22
// 156.830 us; speedup vs baseline: 1.0315x; 1.0315x over previous
//
#include <hip/hip_runtime.h>

#define BATCH 8
#define SEQ   8192
#define NH    16
#define DP    64
#define ROWF  (NH*DP)        // 1024 floats = 4KB per t (all heads)
#define HGRP  4              // heads per block
#define NTHR  512            // 8 waves = 4 heads x 2 n-halves
#define KT    64             // t per phase = TWO mfma-K depths (was 32)
#define RS    260            // dword row-stride (2-way bank alias = free; r19)

typedef __attribute__((ext_vector_type(8))) short bf16x8;
typedef __attribute__((ext_vector_type(4))) float f32x4;

// round-to-nearest-even f32->bf16 pair pack: lo -> low 16 bits (even t = lower k)
static __device__ __forceinline__ unsigned pk2(float lo, float hi) {
    unsigned a = __builtin_bit_cast(unsigned, lo);
    unsigned b = __builtin_bit_cast(unsigned, hi);
    a = (a + 0x7FFFu + ((a >> 16) & 1u)) >> 16;
    b = (b + 0x7FFFu + ((b >> 16) & 1u)) & 0xFFFF0000u;
    return (a & 0xFFFFu) | b;
}

// ---------------------------------------------------------------------------
// k_partial (MFMA, KT=64 phase-doubling): per (b,h,chunk):
// C[64p][64n] = sum_t (w*X)[t][p]*B[t][n]  (GEMM, K=t).
// r18-r21 found phase time pinned ~12K cyc for 64KB phases across ALL sync
// structures (3-barrier, dbuf-1-barrier, deep ring + counted vmcnt) -> either
// per-phase fixed overhead or a ~13.5 GB/s/CU delivery-rate cap. This round
// doubles the phase (128KB, 4 phases/block, ONE barrier each) to distinguish:
// overhead amortizes -> ~2x fewer stalls; rate-cap -> phase time doubles, dur
// unchanged -> roofline. Register staging in HALF-sets: only one 32-VGPR set
// held across a barrier (RA cap 128 via launch_bounds(512,2), the known-safe
// config; r20 showed 3 full sets get silently re-serialized at cap 80).
// ---------------------------------------------------------------------------
template<int NBLK>
__global__ __launch_bounds__(NTHR, 2)
void k_partial(const float* __restrict__ Xg, const float* __restrict__ Ag,
               const float* __restrict__ Bg, float* __restrict__ part,
               float* __restrict__ blockA)
{
    constexpr int TB  = SEQ / NBLK;   // 256 (NBLK=32) or 512 (NBLK=16)
    constexpr int Q   = TB / 64;      // 4 or 8
    constexpr int NKT = TB / KT;      // 4 or 8 phases

    __shared__ unsigned XL[2][32][RS];   // [buf][t-pair][row] w*X bf16x2 (66.6KB)
    __shared__ unsigned BL[2][32][RS];   // same for B (66.6KB)
    __shared__ float    WT[HGRP][TB];    // 4-8KB; total <= 141KB -> 1 block/CU

    const int gid  = blockIdx.x;            // b*(4*NBLK) + hg*NBLK + blk
    const int blk  = gid % NBLK;
    const int hg   = (gid / NBLK) & 3;
    const int b    = gid / (4 * NBLK);
    const int tid  = threadIdx.x;
    const int w    = tid >> 6;              // 0..7
    const int lane = tid & 63;
    const int hloc = w >> 1;                // head within group
    const int nh   = w & 1;                 // n-half
    const int h    = hg * HGRP + hloc;
    const int t0   = blk * TB;

    // ---- per-wave scan of A column h (redundant across the 2 waves/head) ----
    float c[Q];
    {
        const size_t abase = ((size_t)(b * SEQ + t0 + lane * Q)) * NH + h;
        float run = 0.f;
        #pragma unroll
        for (int k = 0; k < Q; ++k) { run += Ag[abase + (size_t)k * NH]; c[k] = run; }
    }
    float tsum = c[Q - 1], s = tsum;
    #pragma unroll
    for (int d = 1; d < 64; d <<= 1) {
        float o = __shfl_up(s, d, 64);
        if (lane >= d) s += o;
    }
    const float total = __shfl(s, 63, 64);
    const float excl  = s - tsum;
    if (nh == 0) {
        #pragma unroll
        for (int k = 0; k < Q; ++k)
            WT[hloc][lane * Q + k] = __expf(total - (excl + c[k]));
        if (lane == 63) blockA[(size_t)(b * NH + h) * NBLK + blk] = total;
    }

    f32x4 acc[4][2];
    #pragma unroll
    for (int mi = 0; mi < 4; ++mi)
        #pragma unroll
        for (int ni = 0; ni < 2; ++ni) acc[mi][ni] = (f32x4){0.f, 0.f, 0.f, 0.f};

    const int hl = lane >> 4;                // head this lane stages
    const int p4 = (lane & 15) * 4;          // 4 consecutive p
    const size_t gbase = (size_t)(b * SEQ + t0) * ROWF + hg * (HGRP * DP) + hl * DP + p4;

    // half-set = 4 t-rows (w*8 + half*4 + {0..3}) of X and B: 8 float4 = 32 VGPR
    auto issueH = [&](int k, int half, float4* lx, float4* lb) {
        if (k >= NKT) return;
        const size_t tb = gbase + (size_t)(k * KT + w * 8 + half * 4) * ROWF;
        #pragma unroll
        for (int i = 0; i < 4; ++i) {
            lx[i] = *(const float4*)(Xg + tb + (size_t)i * ROWF);
            lb[i] = *(const float4*)(Bg + tb + (size_t)i * ROWF);
        }
    };
    auto cwriteH = [&](int k, int buf, int half, const float4* lx, const float4* lb) {
        const int tBase = k * KT + w * 8 + half * 4;       // first t of this half
        #pragma unroll
        for (int q2 = 0; q2 < 2; ++q2) {
            const float w0 = WT[hl][tBase + 2 * q2];
            const float w1 = WT[hl][tBase + 2 * q2 + 1];
            const int   tp = w * 4 + half * 2 + q2;        // t-pair slot (0..31)
            const float* x0 = (const float*)&lx[2 * q2];
            const float* x1 = (const float*)&lx[2 * q2 + 1];
            const float* b0 = (const float*)&lb[2 * q2];
            const float* b1 = (const float*)&lb[2 * q2 + 1];
            uint4 xv, bv;
            xv.x = pk2(x0[0] * w0, x1[0] * w1);
            xv.y = pk2(x0[1] * w0, x1[1] * w1);
            xv.z = pk2(x0[2] * w0, x1[2] * w1);
            xv.w = pk2(x0[3] * w0, x1[3] * w1);
            bv.x = pk2(b0[0], b1[0]);
            bv.y = pk2(b0[1], b1[1]);
            bv.z = pk2(b0[2], b1[2]);
            bv.w = pk2(b0[3], b1[3]);
            *(uint4*)&XL[buf][tp][hl * 64 + p4] = xv;      // one ds_write_b128
            *(uint4*)&BL[buf][tp][hl * 64 + p4] = bv;
        }
    };
    // one K-half (32 t) of fragments + 8 mfma; kh = 0 or 1
    auto computeKH = [&](int buf, int kh) {
        const int r  = lane & 15;
        const int kg = lane >> 4;
        uint4 af[4], bf[2];
        #pragma unroll
        for (int mi = 0; mi < 4; ++mi) {
            const int row = hloc * 64 + mi * 16 + r;
            af[mi].x = XL[buf][kh * 16 + kg * 4 + 0][row];
            af[mi].y = XL[buf][kh * 16 + kg * 4 + 1][row];
            af[mi].z = XL[buf][kh * 16 + kg * 4 + 2][row];
            af[mi].w = XL[buf][kh * 16 + kg * 4 + 3][row];
        }
        #pragma unroll
        for (int ni = 0; ni < 2; ++ni) {
            const int row = hloc * 64 + nh * 32 + ni * 16 + r;
            bf[ni].x = BL[buf][kh * 16 + kg * 4 + 0][row];
            bf[ni].y = BL[buf][kh * 16 + kg * 4 + 1][row];
            bf[ni].z = BL[buf][kh * 16 + kg * 4 + 2][row];
            bf[ni].w = BL[buf][kh * 16 + kg * 4 + 3][row];
        }
        #pragma unroll
        for (int mi = 0; mi < 4; ++mi) {
            const bf16x8 a = __builtin_bit_cast(bf16x8, af[mi]);
            #pragma unroll
            for (int ni = 0; ni < 2; ++ni)
                acc[mi][ni] = __builtin_amdgcn_mfma_f32_16x16x32_bf16(
                                  a, __builtin_bit_cast(bf16x8, bf[ni]),
                                  acc[mi][ni], 0, 0, 0);
        }
    };

    // ---- pipeline: ONE barrier per phase; only H0-next held across it ----
    float4 h0x[4], h0b[4], h1x[4], h1b[4];
    __syncthreads();                          // WT visible (drains scan loads)
    issueH(0, 0, h0x, h0b);                   // prologue: H0 of phase 0

    #pragma unroll 1
    for (int k = 0; k < NKT; ++k) {
        const int buf = k & 1;
        issueH(k, 1, h1x, h1b);               // H1 of current phase (short lead)
        cwriteH(k, buf, 0, h0x, h0b);         // waits H0 loads
        issueH(k + 1, 0, h0x, h0b);           // H0 of next phase (held across barrier)
        cwriteH(k, buf, 1, h1x, h1b);         // waits H1 loads
        asm volatile("s_waitcnt lgkmcnt(0)" ::: "memory");
        __builtin_amdgcn_s_barrier();         // phase data published
        __builtin_amdgcn_sched_barrier(0);
        computeKH(buf, 0);
        computeKH(buf, 1);
        // safety of rewrite: cwrite(k+2) to this buf happens after barrier(k+1),
        // and our ds_reads complete before we pass barrier(k+1). (r19 proof.)
    }

    // ---- epilogue: C/D layout (m89): col = lane&15, row = (lane>>4)*4 + reg ----
    float* dst = part + ((size_t)(b * NH + h) * NBLK + blk) * 4096;
    {
        const int r  = lane & 15;
        const int cg = lane >> 4;
        #pragma unroll
        for (int mi = 0; mi < 4; ++mi)
            #pragma unroll
            for (int ni = 0; ni < 2; ++ni)
                #pragma unroll
                for (int rr = 0; rr < 4; ++rr)
                    dst[(mi * 16 + cg * 4 + rr) * 64 + nh * 32 + ni * 16 + r] =
                        acc[mi][ni][rr];
    }
}

// ---------------------------------------------------------------------------
// k_combine (scales fused): out[bh,p,n] = sum_c exp(suffixA) * part[bh,c,p,n]
// ---------------------------------------------------------------------------
__global__ __launch_bounds__(256)
void k_combine(const float* __restrict__ part, const float* __restrict__ blockA,
               float* __restrict__ out, int nblk)
{
    const int idx = blockIdx.x * 256 + threadIdx.x;   // 0..524287
    const int bh  = idx >> 12;
    const int e   = idx & 4095;
    float r = 0.f, run = 0.f;
    for (int q = nblk - 1; q >= 0; --q) {             // suffix order
        r   += __expf(run) * part[((size_t)bh * nblk + q) * 4096 + e];
        run += blockA[bh * nblk + q];
    }
    out[idx] = r;
}

// ---------------------------------------------------------------------------
extern "C" void kernel_launch(void* const* d_in, const int* in_sizes, int n_in,
                              void* d_out, int out_size, void* d_ws, size_t ws_size,
                              hipStream_t stream)
{
    const float* X = (const float*)d_in[0];
    const float* A = (const float*)d_in[1];
    const float* B = (const float*)d_in[2];
    float* out     = (float*)d_out;

    const size_t need32 = ((size_t)BATCH * NH * 32 * 4096 + (size_t)BATCH * NH * 32) * 4;
    const int nblk = (ws_size >= need32) ? 32 : 16;

    float* part   = (float*)d_ws;
    float* blockA = part + (size_t)BATCH * NH * nblk * 4096;

    if (nblk == 32)
        hipLaunchKernelGGL((k_partial<32>), dim3(BATCH * 4 * 32), dim3(NTHR), 0, stream,
                           X, A, B, part, blockA);
    else
        hipLaunchKernelGGL((k_partial<16>), dim3(BATCH * 4 * 16), dim3(NTHR), 0, stream,
                           X, A, B, part, blockA);

    hipLaunchKernelGGL(k_combine, dim3((BATCH * NH * 4096) / 256), dim3(256), 0, stream,
                       part, blockA, out, nblk);
}

// Round 23
// 135.750 us; speedup vs baseline: 1.1917x; 1.1553x over previous
//
#include <hip/hip_runtime.h>

#define BATCH 8
#define SEQ   8192
#define NH    16
#define DP    64
#define ROWF  (NH*DP)        // 1024 floats = 4KB per t (all heads)
#define HGRP  4              // heads per block
#define NTHR  512            // 8 waves = 4 heads x 2 n-halves
#define KT    32             // t per k-tile = one mfma K-depth
#define RS    260            // dword row-stride (2-way bank alias = free; r19)

typedef __attribute__((ext_vector_type(8))) short bf16x8;
typedef __attribute__((ext_vector_type(4))) float f32x4;

// round-to-nearest-even f32->bf16 pair pack: lo -> low 16 bits (even t = lower k)
static __device__ __forceinline__ unsigned pk2(float lo, float hi) {
    unsigned a = __builtin_bit_cast(unsigned, lo);
    unsigned b = __builtin_bit_cast(unsigned, hi);
    a = (a + 0x7FFFu + ((a >> 16) & 1u)) >> 16;
    b = (b + 0x7FFFu + ((b >> 16) & 1u)) & 0xFFFF0000u;
    return (a & 0xFFFFu) | b;
}

// ---------------------------------------------------------------------------
// k_partial (r18 MFMA structure + XCD-GATHER remap): per (b,h,chunk):
// C[64p][64n] = sum_t (w*X)[t][p]*B[t][n]  (GEMM, K=t).
// r18-r22: delivery pinned ~13.5 GB/s/CU across all sync structures & phase
// sizes -> rate cap, not latency. Candidate mechanism: each block reads its
// head-group QUARTER of every 4KB row (1KB@4KB stride), the 4 quarters land
// on 4 different XCDs -> no L2 sees a sequential miss stream, DRAM pages
// split 4 ways. FIX UNDER TEST: remap blockIdx so the 4 hg-blocks of each
// (b,chunk) get gid == same value mod 8 -> SAME XCD (round-robin dispatch,
// m09/m157) -> their quarter-reads merge in that XCD's L2 into a sequential
// HBM stream. They launch within 32 gids of each other (drift small).
// ---------------------------------------------------------------------------
template<int NBLK>
__global__ __launch_bounds__(NTHR)
void k_partial(const float* __restrict__ Xg, const float* __restrict__ Ag,
               const float* __restrict__ Bg, float* __restrict__ part,
               float* __restrict__ blockA)
{
    constexpr int TB  = SEQ / NBLK;   // 256 (NBLK=32)
    constexpr int Q   = TB / 64;      // 4
    constexpr int NKT = TB / KT;      // 8

    __shared__ unsigned XL[16][RS];   // 16 t-pairs x 256 rows (+pad) of w*X bf16x2
    __shared__ unsigned BL[16][RS];   // same for B
    __shared__ float    WT[HGRP][TB]; // per-head weights for this chunk

    // ---- XCD-gather remap: p -> (b, hg, blk) with 4 hg's of a (b,blk) on one XCD
    const int p    = blockIdx.x;            // 0 .. 4*BATCH*NBLK-1
    const int xcd  = p & 7;
    const int q_   = p >> 3;
    const int hg   = q_ & 3;
    const int sidx = q_ >> 2;
    const int idx  = sidx * 8 + xcd;        // 0 .. BATCH*NBLK-1
    const int blk  = idx % NBLK;
    const int b    = idx / NBLK;

    const int tid  = threadIdx.x;
    const int w    = tid >> 6;              // 0..7
    const int lane = tid & 63;
    const int hloc = w >> 1;                // head within group
    const int nh   = w & 1;                 // n-half
    const int h    = hg * HGRP + hloc;
    const int t0   = blk * TB;

    // ---- per-wave scan of A column h (redundant across the 2 waves/head) ----
    float c[Q];
    {
        const size_t abase = ((size_t)(b * SEQ + t0 + lane * Q)) * NH + h;
        float run = 0.f;
        #pragma unroll
        for (int k = 0; k < Q; ++k) { run += Ag[abase + (size_t)k * NH]; c[k] = run; }
    }
    float tsum = c[Q - 1], s = tsum;
    #pragma unroll
    for (int d = 1; d < 64; d <<= 1) {
        float o = __shfl_up(s, d, 64);
        if (lane >= d) s += o;
    }
    const float total = __shfl(s, 63, 64);
    const float excl  = s - tsum;
    if (nh == 0) {
        #pragma unroll
        for (int k = 0; k < Q; ++k)
            WT[hloc][lane * Q + k] = __expf(total - (excl + c[k]));
        if (lane == 63) blockA[(size_t)(b * NH + h) * NBLK + blk] = total;
    }

    // ---- accumulators: 4 m-tiles x 2 n-tiles of 16x16 ----
    f32x4 acc[4][2];
    #pragma unroll
    for (int mi = 0; mi < 4; ++mi)
        #pragma unroll
        for (int ni = 0; ni < 2; ++ni) acc[mi][ni] = (f32x4){0.f, 0.f, 0.f, 0.f};

    // staging geometry: one wave-load = one t-row of the 4-head slice (1KB)
    const int hl = lane >> 4;                // head this lane stages
    const int p4 = (lane & 15) * 4;          // 4 consecutive p
    const size_t gbase = (size_t)(b * SEQ + t0) * ROWF + hg * (HGRP * DP) + hl * DP + p4;

    auto issue = [&](int k, float4* lx, float4* lb) {
        if (k >= NKT) return;
        const size_t tb = gbase + (size_t)(k * KT + w * 4) * ROWF;
        #pragma unroll
        for (int i = 0; i < 4; ++i) {
            lx[i] = *(const float4*)(Xg + tb + (size_t)i * ROWF);
            lb[i] = *(const float4*)(Bg + tb + (size_t)i * ROWF);
        }
    };
    auto cwrite = [&](int k, const float4* lx, const float4* lb) {
        const int tIn = k * KT + w * 4;            // within-chunk t of lx[0]
        #pragma unroll
        for (int q2 = 0; q2 < 2; ++q2) {
            const float w0 = WT[hl][tIn + 2 * q2];
            const float w1 = WT[hl][tIn + 2 * q2 + 1];
            const int   tp = w * 2 + q2;           // t-pair slot in tile (0..15)
            const float* x0 = (const float*)&lx[2 * q2];
            const float* x1 = (const float*)&lx[2 * q2 + 1];
            const float* b0 = (const float*)&lb[2 * q2];
            const float* b1 = (const float*)&lb[2 * q2 + 1];
            uint4 xv, bv;
            xv.x = pk2(x0[0] * w0, x1[0] * w1);
            xv.y = pk2(x0[1] * w0, x1[1] * w1);
            xv.z = pk2(x0[2] * w0, x1[2] * w1);
            xv.w = pk2(x0[3] * w0, x1[3] * w1);
            bv.x = pk2(b0[0], b1[0]);
            bv.y = pk2(b0[1], b1[1]);
            bv.z = pk2(b0[2], b1[2]);
            bv.w = pk2(b0[3], b1[3]);
            *(uint4*)&XL[tp][hl * 64 + p4] = xv;   // one ds_write_b128
            *(uint4*)&BL[tp][hl * 64 + p4] = bv;
        }
    };
    auto compute = [&]() {
        const int r  = lane & 15;
        const int kg = lane >> 4;
        uint4 af[4], bf[2];
        #pragma unroll
        for (int mi = 0; mi < 4; ++mi) {
            const int row = hloc * 64 + mi * 16 + r;
            af[mi].x = XL[kg * 4 + 0][row];
            af[mi].y = XL[kg * 4 + 1][row];
            af[mi].z = XL[kg * 4 + 2][row];
            af[mi].w = XL[kg * 4 + 3][row];
        }
        #pragma unroll
        for (int ni = 0; ni < 2; ++ni) {
            const int row = hloc * 64 + nh * 32 + ni * 16 + r;
            bf[ni].x = BL[kg * 4 + 0][row];
            bf[ni].y = BL[kg * 4 + 1][row];
            bf[ni].z = BL[kg * 4 + 2][row];
            bf[ni].w = BL[kg * 4 + 3][row];
        }
        #pragma unroll
        for (int mi = 0; mi < 4; ++mi) {
            const bf16x8 a = __builtin_bit_cast(bf16x8, af[mi]);
            #pragma unroll
            for (int ni = 0; ni < 2; ++ni) {
                const bf16x8 bb = __builtin_bit_cast(bf16x8, bf[ni]);
                acc[mi][ni] = __builtin_amdgcn_mfma_f32_16x16x32_bf16(
                                  a, bb, acc[mi][ni], 0, 0, 0);
            }
        }
    };

    // ---- pipeline: 2 reg-sets, single LDS buffer (r18's best-measured) ----
    float4 sx0[4], sb0[4], sx1[4], sb1[4];
    issue(0, sx0, sb0);
    issue(1, sx1, sb1);
    __syncthreads();                         // WT (and scan) visible

    #pragma unroll 1
    for (int k = 0; k < NKT; k += 2) {
        cwrite(k, sx0, sb0);                 // compiler waits set0's loads
        issue(k + 2, sx0, sb0);
        asm volatile("s_waitcnt lgkmcnt(0)" ::: "memory");
        __builtin_amdgcn_s_barrier();
        __builtin_amdgcn_sched_barrier(0);
        compute();
        __builtin_amdgcn_s_barrier();        // all frag reads done before rewrite

        cwrite(k + 1, sx1, sb1);
        issue(k + 3, sx1, sb1);
        asm volatile("s_waitcnt lgkmcnt(0)" ::: "memory");
        __builtin_amdgcn_s_barrier();
        __builtin_amdgcn_sched_barrier(0);
        compute();
        __builtin_amdgcn_s_barrier();
    }

    // ---- epilogue: C/D layout (m89): col = lane&15, row = (lane>>4)*4 + reg ----
    float* dst = part + ((size_t)(b * NH + h) * NBLK + blk) * 4096;
    {
        const int r  = lane & 15;
        const int cg = lane >> 4;
        #pragma unroll
        for (int mi = 0; mi < 4; ++mi)
            #pragma unroll
            for (int ni = 0; ni < 2; ++ni)
                #pragma unroll
                for (int rr = 0; rr < 4; ++rr)
                    dst[(mi * 16 + cg * 4 + rr) * 64 + nh * 32 + ni * 16 + r] =
                        acc[mi][ni][rr];
    }
}

// ---------------------------------------------------------------------------
// k_combine (scales fused): out[bh,p,n] = sum_c exp(suffixA) * part[bh,c,p,n]
// ---------------------------------------------------------------------------
__global__ __launch_bounds__(256)
void k_combine(const float* __restrict__ part, const float* __restrict__ blockA,
               float* __restrict__ out, int nblk)
{
    const int idx = blockIdx.x * 256 + threadIdx.x;   // 0..524287
    const int bh  = idx >> 12;
    const int e   = idx & 4095;
    float r = 0.f, run = 0.f;
    for (int q = nblk - 1; q >= 0; --q) {             // suffix order
        r   += __expf(run) * part[((size_t)bh * nblk + q) * 4096 + e];
        run += blockA[bh * nblk + q];
    }
    out[idx] = r;
}

// ---------------------------------------------------------------------------
extern "C" void kernel_launch(void* const* d_in, const int* in_sizes, int n_in,
                              void* d_out, int out_size, void* d_ws, size_t ws_size,
                              hipStream_t stream)
{
    const float* X = (const float*)d_in[0];
    const float* A = (const float*)d_in[1];
    const float* B = (const float*)d_in[2];
    float* out     = (float*)d_out;

    const size_t need32 = ((size_t)BATCH * NH * 32 * 4096 + (size_t)BATCH * NH * 32) * 4;
    const int nblk = (ws_size >= need32) ? 32 : 16;

    float* part   = (float*)d_ws;
    float* blockA = part + (size_t)BATCH * NH * nblk * 4096;

    if (nblk == 32)
        hipLaunchKernelGGL((k_partial<32>), dim3(BATCH * 4 * 32), dim3(NTHR), 0, stream,
                           X, A, B, part, blockA);
    else
        hipLaunchKernelGGL((k_partial<16>), dim3(BATCH * 4 * 16), dim3(NTHR), 0, stream,
                           X, A, B, part, blockA);

    hipLaunchKernelGGL(k_combine, dim3((BATCH * NH * 4096) / 256), dim3(256), 0, stream,
                       part, blockA, out, nblk);
}